// Round 1
// baseline (1105.709 us; speedup 1.0000x reference)
//
#include <hip/hip_runtime.h>

typedef _Float16 half_t;
typedef __attribute__((ext_vector_type(8))) _Float16 half8;
typedef __attribute__((ext_vector_type(4))) float f32x4;

#define WS_W1   0                          // 768*256 fp16 = 393216 B
#define WS_W2   (768*256*2)                // 256*256 fp16 = 131072 B
#define WS_BIAS (WS_W2 + 256*256*2)        // 8*64*64 fp32 = 131072 B
#define WS_QKV  (WS_BIAS + 8*64*64*4)      // B_*8*3*2048 fp16
#define QK_SCALE 0.17677669529663687f      // 32^-0.5

// ---------------- prep: weight fp32->fp16 + rpb bias gather ----------------
__global__ __launch_bounds__(256) void prep_kernel(
    const float* __restrict__ qkv_w, const float* __restrict__ proj_w,
    const float* __restrict__ rpb, const int* __restrict__ rel_idx,
    char* __restrict__ ws) {
  int tid = blockIdx.x * 256 + threadIdx.x;
  half_t* W1 = (half_t*)(ws + WS_W1);
  half_t* W2 = (half_t*)(ws + WS_W2);
  float* BIAS = (float*)(ws + WS_BIAS);
  if (tid < 768 * 256) {
    int n = tid >> 8;
    float v = qkv_w[tid];
    if (n < 256) v *= QK_SCALE;          // fold q-scale into Wq
    W1[tid] = (half_t)v;
  }
  if (tid < 256 * 256) W2[tid] = (half_t)proj_w[tid];
  if (tid < 8 * 64 * 64) {
    int h = tid >> 12;
    int ij = tid & 4095;
    BIAS[tid] = rpb[rel_idx[ij] * 8 + h];
  }
}

// ---------------- kernel A: QKV GEMM per window ----------------
// block = 1 window (64 tokens), 256 thr = 4 waves. GEMM [64 x 768 x 256].
__global__ __launch_bounds__(256) void qkv_kernel(
    const float* __restrict__ x, const float* __restrict__ qkv_b,
    char* __restrict__ ws) {
  __shared__ __align__(16) half_t Xs[64 * 264];   // padded stride 264 (16B-aligned rows)
  const int b = blockIdx.x;
  const int tid = threadIdx.x;
  const float4* xw = (const float4*)(x + (size_t)b * 16384);
  // stage x window -> fp16 LDS, coalesced float4 reads
#pragma unroll
  for (int i = 0; i < 16; ++i) {
    int idx4 = tid + i * 256;
    float4 v = xw[idx4];
    int e = idx4 << 2;
    int row = e >> 8, col = e & 255;
    union { half_t h[4]; long long ll; } pk;
    pk.h[0] = (half_t)v.x; pk.h[1] = (half_t)v.y;
    pk.h[2] = (half_t)v.z; pk.h[3] = (half_t)v.w;
    *(long long*)(&Xs[row * 264 + col]) = pk.ll;
  }
  __syncthreads();
  const int wave = tid >> 6, lane = tid & 63;
  const int l16 = lane & 15, quad = lane >> 4;
  const half_t* W1 = (const half_t*)(ws + WS_W1);
  half_t* QKV = (half_t*)(ws + WS_QKV);
  const int nwb = wave * 192;                     // each wave: 192 of 768 out-dims
  for (int chunk = 0; chunk < 4; ++chunk) {       // 48 dims (3 n-tiles) per chunk
    f32x4 acc[3][4];
#pragma unroll
    for (int nt = 0; nt < 3; ++nt)
#pragma unroll
      for (int mt = 0; mt < 4; ++mt)
        acc[nt][mt] = (f32x4){0.f, 0.f, 0.f, 0.f};
    const int nbase = nwb + chunk * 48;
#pragma unroll
    for (int ks = 0; ks < 8; ++ks) {
      half8 af[4];
#pragma unroll
      for (int mt = 0; mt < 4; ++mt)
        af[mt] = *(const half8*)(&Xs[(16 * mt + l16) * 264 + 32 * ks + quad * 8]);
#pragma unroll
      for (int nt = 0; nt < 3; ++nt) {
        half8 bf = *(const half8*)(&W1[(size_t)(nbase + 16 * nt + l16) * 256 + 32 * ks + quad * 8]);
#pragma unroll
        for (int mt = 0; mt < 4; ++mt)
          acc[nt][mt] = __builtin_amdgcn_mfma_f32_16x16x32_f16(af[mt], bf, acc[nt][mt], 0, 0, 0);
      }
    }
    // epilogue: + bias, scatter into Q [t][d], K [t][d], V^T [d][t] (fp16)
#pragma unroll
    for (int nt = 0; nt < 3; ++nt) {
      int n = nbase + 16 * nt + l16;
      float bias = qkv_b[n];
      if (n < 256) bias *= QK_SCALE;
      int part = n >> 8;           // 0=q 1=k 2=v (uniform per nt since tiles are 16-aligned)
      int h = (n >> 5) & 7;
      int d = n & 31;
      half_t* base = QKV + ((size_t)(b * 8 + h) * 3 + part) * 2048;
#pragma unroll
      for (int mt = 0; mt < 4; ++mt) {
#pragma unroll
        for (int r = 0; r < 4; ++r) {
          int t = 16 * mt + quad * 4 + r;
          float v = acc[nt][mt][r] + bias;
          if (part < 2) base[t * 32 + d] = (half_t)v;
          else          base[d * 64 + t] = (half_t)v;
        }
      }
    }
  }
}

// ---------------- kernel B: attention + proj per window ----------------
// block = 1 window, 4 waves; wave w handles heads 2w, 2w+1, then proj n-slice.
__global__ __launch_bounds__(256) void attn_kernel(
    const float* __restrict__ mask, const float* __restrict__ proj_b,
    const char* __restrict__ ws, float* __restrict__ out, int nW) {
  __shared__ __align__(16) half_t AO[64 * 264];     // attn output [64 tok][256 dims], padded
  __shared__ __align__(16) half_t Pbuf[4][16 * 72]; // per-wave P transpose buffer (16 rows)
  const int b = blockIdx.x;
  const int tid = threadIdx.x;
  const int wave = tid >> 6, lane = tid & 63;
  const int l16 = lane & 15, quad = lane >> 4;
  const half_t* QKV = (const half_t*)(ws + WS_QKV);
  const float* BIAS = (const float*)(ws + WS_BIAS);
  const float* maskw = mask + (size_t)(b % nW) * 4096;
  half_t* P = Pbuf[wave];
  const f32x4 z4 = {0.f, 0.f, 0.f, 0.f};

  for (int hh = 0; hh < 2; ++hh) {
    const int h = wave * 2 + hh;
    const half_t* Qb = QKV + (size_t)(b * 8 + h) * 3 * 2048;
    const half_t* Kb = Qb + 2048;
    const half_t* Vb = Qb + 4096;                   // V^T [32 d][64 t]
    half8 qf[4], kf[4];
#pragma unroll
    for (int mt = 0; mt < 4; ++mt)
      qf[mt] = *(const half8*)(Qb + (16 * mt + l16) * 32 + quad * 8);
#pragma unroll
    for (int nt = 0; nt < 4; ++nt)
      kf[nt] = *(const half8*)(Kb + (16 * nt + l16) * 32 + quad * 8);
    // S = (q*scale) @ k^T  — K-dim = 32 = one MFMA step
    f32x4 S[4][4];
#pragma unroll
    for (int mt = 0; mt < 4; ++mt)
#pragma unroll
      for (int nt = 0; nt < 4; ++nt)
        S[mt][nt] = __builtin_amdgcn_mfma_f32_16x16x32_f16(qf[mt], kf[nt], z4, 0, 0, 0);
    // + rel-pos bias + mask, softmax (rows live in one quad: shfl_xor 1,2,4,8)
    float linv[4][4];
#pragma unroll
    for (int mt = 0; mt < 4; ++mt) {
#pragma unroll
      for (int r = 0; r < 4; ++r) {
        const int i = 16 * mt + quad * 4 + r;
        const float* bp = BIAS + h * 4096 + i * 64;
        const float* mp = maskw + i * 64;
#pragma unroll
        for (int nt = 0; nt < 4; ++nt) {
          int j = 16 * nt + l16;
          S[mt][nt][r] += bp[j] + mp[j];
        }
        float mx = fmaxf(fmaxf(S[mt][0][r], S[mt][1][r]), fmaxf(S[mt][2][r], S[mt][3][r]));
#pragma unroll
        for (int o = 1; o < 16; o <<= 1) mx = fmaxf(mx, __shfl_xor(mx, o, 64));
        float s = 0.f;
#pragma unroll
        for (int nt = 0; nt < 4; ++nt) {
          float e = exp2f((S[mt][nt][r] - mx) * 1.44269504f);
          S[mt][nt][r] = e;
          s += e;
        }
#pragma unroll
        for (int o = 1; o < 16; o <<= 1) s += __shfl_xor(s, o, 64);
        linv[mt][r] = 1.f / s;
      }
    }
    // O = P @ V ; P goes C-layout -> LDS -> A-layout, 16 rows (one mt) at a time
    half8 vf[2][2];
#pragma unroll
    for (int nt = 0; nt < 2; ++nt)
#pragma unroll
      for (int ks = 0; ks < 2; ++ks)
        vf[nt][ks] = *(const half8*)(Vb + (16 * nt + l16) * 64 + 32 * ks + quad * 8);
#pragma unroll
    for (int mt = 0; mt < 4; ++mt) {
#pragma unroll
      for (int nt = 0; nt < 4; ++nt)
#pragma unroll
        for (int r = 0; r < 4; ++r)
          P[(quad * 4 + r) * 72 + 16 * nt + l16] = (half_t)(S[mt][nt][r] * linv[mt][r]);
      f32x4 O[2] = {z4, z4};
#pragma unroll
      for (int ks = 0; ks < 2; ++ks) {
        half8 pf = *(const half8*)(P + l16 * 72 + 32 * ks + quad * 8);
#pragma unroll
        for (int nt = 0; nt < 2; ++nt)
          O[nt] = __builtin_amdgcn_mfma_f32_16x16x32_f16(pf, vf[nt][ks], O[nt], 0, 0, 0);
      }
#pragma unroll
      for (int nt = 0; nt < 2; ++nt)
#pragma unroll
        for (int r = 0; r < 4; ++r)
          AO[(16 * mt + quad * 4 + r) * 264 + h * 32 + 16 * nt + l16] = (half_t)O[nt][r];
    }
  }
  __syncthreads();
  // proj: out = AO[64x256] @ W2^T + b ; wave w covers out-dims [64w, 64w+64)
  const half_t* W2 = (const half_t*)(ws + WS_W2);
  f32x4 C[4][4];
#pragma unroll
  for (int nt = 0; nt < 4; ++nt)
#pragma unroll
    for (int mt = 0; mt < 4; ++mt)
      C[nt][mt] = z4;
  const int nb = wave * 64;
#pragma unroll
  for (int ks = 0; ks < 8; ++ks) {
    half8 af[4];
#pragma unroll
    for (int mt = 0; mt < 4; ++mt)
      af[mt] = *(const half8*)(AO + (16 * mt + l16) * 264 + 32 * ks + quad * 8);
#pragma unroll
    for (int nt = 0; nt < 4; ++nt) {
      half8 bf = *(const half8*)(W2 + (size_t)(nb + 16 * nt + l16) * 256 + 32 * ks + quad * 8);
#pragma unroll
      for (int mt = 0; mt < 4; ++mt)
        C[nt][mt] = __builtin_amdgcn_mfma_f32_16x16x32_f16(af[mt], bf, C[nt][mt], 0, 0, 0);
    }
  }
#pragma unroll
  for (int nt = 0; nt < 4; ++nt) {
    int c = nb + 16 * nt + l16;
    float pb = proj_b[c];
#pragma unroll
    for (int mt = 0; mt < 4; ++mt)
#pragma unroll
      for (int r = 0; r < 4; ++r) {
        int t = 16 * mt + quad * 4 + r;
        out[(size_t)b * 16384 + t * 256 + c] = C[nt][mt][r] + pb;
      }
  }
}

extern "C" void kernel_launch(void* const* d_in, const int* in_sizes, int n_in,
                              void* d_out, int out_size, void* d_ws, size_t ws_size,
                              hipStream_t stream) {
  const float* x      = (const float*)d_in[0];
  const float* mask   = (const float*)d_in[1];
  const float* rpb    = (const float*)d_in[2];
  const float* qkv_w  = (const float*)d_in[3];
  const float* qkv_b  = (const float*)d_in[4];
  const float* proj_w = (const float*)d_in[5];
  const float* proj_b = (const float*)d_in[6];
  const int*   rel    = (const int*)d_in[7];
  float* out = (float*)d_out;
  char* ws = (char*)d_ws;
  int B_ = in_sizes[0] / 16384;   // windows*batch
  int nW = in_sizes[1] / 4096;    // mask windows
  hipLaunchKernelGGL(prep_kernel, dim3(768), dim3(256), 0, stream,
                     qkv_w, proj_w, rpb, rel, ws);
  hipLaunchKernelGGL(qkv_kernel, dim3(B_), dim3(256), 0, stream, x, qkv_b, ws);
  hipLaunchKernelGGL(attn_kernel, dim3(B_), dim3(256), 0, stream,
                     mask, proj_b, (const char*)ws, out, nW);
}

// Round 2
// 843.003 us; speedup vs baseline: 1.3116x; 1.3116x over previous
//
#include <hip/hip_runtime.h>

typedef _Float16 half_t;
typedef __attribute__((ext_vector_type(8))) _Float16 half8;
typedef __attribute__((ext_vector_type(4))) float f32x4;

#define WS_W1   0                          // 768*256 fp16 = 393216 B
#define WS_W2   (768*256*2)                // 256*256 fp16 = 131072 B
#define WS_BIAS (WS_W2 + 256*256*2)        // 8*4*4*4*16*4 fp32 = 131072 B (C-fragment permuted)
#define QK_SCALE 0.17677669529663687f      // 32^-0.5

// ---------------- prep: weight fp32->fp16 + rpb bias gather (permuted) ----------------
// BIASP layout: [h][mt][nt][quad][l16][r] so attention reads one coalesced float4
// per C-tile: value = bias[h][i=16mt+4q+r][j=16nt+l16].
__global__ __launch_bounds__(256) void prep_kernel(
    const float* __restrict__ qkv_w, const float* __restrict__ proj_w,
    const float* __restrict__ rpb, const int* __restrict__ rel_idx,
    char* __restrict__ ws) {
  int tid = blockIdx.x * 256 + threadIdx.x;
  half_t* W1 = (half_t*)(ws + WS_W1);
  half_t* W2 = (half_t*)(ws + WS_W2);
  float* BIASP = (float*)(ws + WS_BIAS);
  if (tid < 768 * 256) {
    int n = tid >> 8;
    float v = qkv_w[tid];
    if (n < 256) v *= QK_SCALE;          // fold q-scale into Wq
    W1[tid] = (half_t)v;
  }
  if (tid < 256 * 256) W2[tid] = (half_t)proj_w[tid];
  if (tid < 8 * 4096) {
    int r   = tid & 3;
    int l16 = (tid >> 2) & 15;
    int q   = (tid >> 6) & 3;
    int nt  = (tid >> 8) & 3;
    int mt  = (tid >> 10) & 3;
    int h   = (tid >> 12) & 7;
    int i = 16 * mt + 4 * q + r;
    int j = 16 * nt + l16;
    BIASP[tid] = rpb[rel_idx[i * 64 + j] * 8 + h];
  }
}

// ---------------- fused kernel: QKV GEMM + attention + proj, 1 block / window ----------------
__global__ __launch_bounds__(512, 2) void fused_kernel(
    const float* __restrict__ x, const float* __restrict__ mask,
    const float* __restrict__ qkv_b, const float* __restrict__ proj_b,
    const char* __restrict__ ws, float* __restrict__ out, int nW) {
  // LDS: 33792 + 81920 + 36864 + 8704 = 161280 B  (<= 163840)
  __shared__ __align__(16) half_t Xs[64 * 264];       // x fp16 (later reused as AO)
  __shared__ __align__(16) half_t QK[8][2][64 * 40];  // Q,K per head, row stride 40
  __shared__ __align__(16) half_t VT[8][32 * 72];     // V^T per head, row stride 72
  __shared__ __align__(16) half_t Ms[64 * 68];        // mask fp16, row stride 68

  const int b = blockIdx.x;
  const int tid = threadIdx.x;
  const int wave = tid >> 6, lane = tid & 63;
  const int l16 = lane & 15, quad = lane >> 4;
  const f32x4 z4 = {0.f, 0.f, 0.f, 0.f};

  // ---- phase 0: stage x (fp32->fp16) and mask into LDS, coalesced float4 ----
  {
    const float4* xw = (const float4*)(x + (size_t)b * 16384);
#pragma unroll
    for (int i = 0; i < 8; ++i) {
      int idx4 = tid + i * 512;
      float4 v = xw[idx4];
      int e = idx4 << 2;
      int row = e >> 8, col = e & 255;
      union { half_t h[4]; long long ll; } pk;
      pk.h[0] = (half_t)v.x; pk.h[1] = (half_t)v.y;
      pk.h[2] = (half_t)v.z; pk.h[3] = (half_t)v.w;
      *(long long*)(&Xs[row * 264 + col]) = pk.ll;
    }
    const float4* mw = (const float4*)(mask + (size_t)(b % nW) * 4096);
#pragma unroll
    for (int i = 0; i < 2; ++i) {
      int idx4 = tid + i * 512;
      float4 v = mw[idx4];
      int e = idx4 << 2;
      int mi = e >> 6, mj = e & 63;
      union { half_t h[4]; long long ll; } pk;
      pk.h[0] = (half_t)v.x; pk.h[1] = (half_t)v.y;
      pk.h[2] = (half_t)v.z; pk.h[3] = (half_t)v.w;
      *(long long*)(&Ms[mi * 68 + mj]) = pk.ll;
    }
  }
  __syncthreads();

  // ---- phase 1: QKV GEMM [64 x 768 x 256]; wave w owns out-dims [96w, 96w+96) ----
  {
    const half_t* W1 = (const half_t*)(ws + WS_W1);
    const int nwb = wave * 96;
    f32x4 acc[6][4];
#pragma unroll
    for (int nt = 0; nt < 6; ++nt)
#pragma unroll
      for (int mt = 0; mt < 4; ++mt) acc[nt][mt] = z4;
#pragma unroll
    for (int ks = 0; ks < 8; ++ks) {
      half8 af[4];
#pragma unroll
      for (int mt = 0; mt < 4; ++mt)
        af[mt] = *(const half8*)(&Xs[(16 * mt + l16) * 264 + 32 * ks + quad * 8]);
#pragma unroll
      for (int nt = 0; nt < 6; ++nt) {
        half8 bf = *(const half8*)(&W1[(size_t)(nwb + 16 * nt + l16) * 256 + 32 * ks + quad * 8]);
#pragma unroll
        for (int mt = 0; mt < 4; ++mt)
          acc[nt][mt] = __builtin_amdgcn_mfma_f32_16x16x32_f16(af[mt], bf, acc[nt][mt], 0, 0, 0);
      }
    }
    // epilogue -> LDS (Q,K as [t][d] stride 40; V^T as [d][t] stride 72)
#pragma unroll
    for (int nt = 0; nt < 6; ++nt) {
      int n = nwb + 16 * nt + l16;
      float bias = qkv_b[n];
      int part = n >> 8;
      if (part == 0) bias *= QK_SCALE;
      int h = (n >> 5) & 7;
      int d = n & 31;
#pragma unroll
      for (int mt = 0; mt < 4; ++mt) {
#pragma unroll
        for (int r = 0; r < 4; ++r) {
          int t = 16 * mt + quad * 4 + r;
          float v = acc[nt][mt][r] + bias;
          if (part < 2) QK[h][part][t * 40 + d] = (half_t)v;
          else          VT[h][d * 72 + t] = (half_t)v;
        }
      }
    }
  }
  __syncthreads();

  // ---- phase 2: attention, wave w = head w ----
  {
    const int h = wave;
    const half_t* Qh = &QK[h][0][0];
    const half_t* Kh = &QK[h][1][0];
    const half_t* Vh = &VT[h][0];
    half8 qf[4], kf[4];
#pragma unroll
    for (int mt = 0; mt < 4; ++mt)
      qf[mt] = *(const half8*)(Qh + (16 * mt + l16) * 40 + quad * 8);
#pragma unroll
    for (int nt = 0; nt < 4; ++nt)
      kf[nt] = *(const half8*)(Kh + (16 * nt + l16) * 40 + quad * 8);
    f32x4 S[4][4];
#pragma unroll
    for (int mt = 0; mt < 4; ++mt)
#pragma unroll
      for (int nt = 0; nt < 4; ++nt)
        S[mt][nt] = __builtin_amdgcn_mfma_f32_16x16x32_f16(qf[mt], kf[nt], z4, 0, 0, 0);

    // + bias (coalesced float4 from permuted table) + mask (LDS), then softmax
    const float4* BP4 = (const float4*)(ws + WS_BIAS);
    float linv[4][4];
#pragma unroll
    for (int mt = 0; mt < 4; ++mt) {
#pragma unroll
      for (int nt = 0; nt < 4; ++nt) {
        float4 bv = BP4[(size_t)(((h * 4 + mt) * 4 + nt) * 64) + quad * 16 + l16];
#pragma unroll
        for (int r = 0; r < 4; ++r)
          S[mt][nt][r] += ((const float*)&bv)[r] +
                          (float)Ms[(16 * mt + quad * 4 + r) * 68 + 16 * nt + l16];
      }
#pragma unroll
      for (int r = 0; r < 4; ++r) {
        float mx = fmaxf(fmaxf(S[mt][0][r], S[mt][1][r]), fmaxf(S[mt][2][r], S[mt][3][r]));
#pragma unroll
        for (int o = 1; o < 16; o <<= 1) mx = fmaxf(mx, __shfl_xor(mx, o, 64));
        float s = 0.f;
#pragma unroll
        for (int nt = 0; nt < 4; ++nt) {
          float e = exp2f((S[mt][nt][r] - mx) * 1.44269504f);
          S[mt][nt][r] = e;
          s += e;
        }
#pragma unroll
        for (int o = 1; o < 16; o <<= 1) s += __shfl_xor(s, o, 64);
        linv[mt][r] = 1.f / s;
      }
    }

    // O = P @ V ; P round-trips C->A layout through the wave's own (dead) Q region
    half8 vf[2][2];
#pragma unroll
    for (int nt = 0; nt < 2; ++nt)
#pragma unroll
      for (int ks = 0; ks < 2; ++ks)
        vf[nt][ks] = *(const half8*)(Vh + (16 * nt + l16) * 72 + 32 * ks + quad * 8);
    half_t* P = &QK[h][0][0];   // wave-private scratch, 16x72 halves
#pragma unroll
    for (int mt = 0; mt < 4; ++mt) {
#pragma unroll
      for (int nt = 0; nt < 4; ++nt)
#pragma unroll
        for (int r = 0; r < 4; ++r)
          P[(quad * 4 + r) * 72 + 16 * nt + l16] = (half_t)(S[mt][nt][r] * linv[mt][r]);
      f32x4 O[2] = {z4, z4};
#pragma unroll
      for (int ks = 0; ks < 2; ++ks) {
        half8 pf = *(const half8*)(P + l16 * 72 + 32 * ks + quad * 8);
#pragma unroll
        for (int nt = 0; nt < 2; ++nt)
          O[nt] = __builtin_amdgcn_mfma_f32_16x16x32_f16(pf, vf[nt][ks], O[nt], 0, 0, 0);
      }
#pragma unroll
      for (int nt = 0; nt < 2; ++nt)
#pragma unroll
        for (int r = 0; r < 4; ++r)
          Xs[(16 * mt + quad * 4 + r) * 264 + h * 32 + 16 * nt + l16] = (half_t)O[nt][r];
    }
  }
  __syncthreads();

  // ---- phase 3: proj out = AO[64x256] @ W2^T + b ; wave w -> out-dims [32w, 32w+32) ----
  {
    const half_t* W2 = (const half_t*)(ws + WS_W2);
    const int nb = wave * 32;
    f32x4 C[2][4];
#pragma unroll
    for (int nt = 0; nt < 2; ++nt)
#pragma unroll
      for (int mt = 0; mt < 4; ++mt) C[nt][mt] = z4;
#pragma unroll
    for (int ks = 0; ks < 8; ++ks) {
      half8 af[4];
#pragma unroll
      for (int mt = 0; mt < 4; ++mt)
        af[mt] = *(const half8*)(&Xs[(16 * mt + l16) * 264 + 32 * ks + quad * 8]);
#pragma unroll
      for (int nt = 0; nt < 2; ++nt) {
        half8 bf = *(const half8*)(&W2[(size_t)(nb + 16 * nt + l16) * 256 + 32 * ks + quad * 8]);
#pragma unroll
        for (int mt = 0; mt < 4; ++mt)
          C[nt][mt] = __builtin_amdgcn_mfma_f32_16x16x32_f16(af[mt], bf, C[nt][mt], 0, 0, 0);
      }
    }
#pragma unroll
    for (int nt = 0; nt < 2; ++nt) {
      int c = nb + 16 * nt + l16;
      float pb = proj_b[c];
#pragma unroll
      for (int mt = 0; mt < 4; ++mt)
#pragma unroll
        for (int r = 0; r < 4; ++r) {
          int t = 16 * mt + quad * 4 + r;
          out[(size_t)b * 16384 + t * 256 + c] = C[nt][mt][r] + pb;
        }
    }
  }
}

extern "C" void kernel_launch(void* const* d_in, const int* in_sizes, int n_in,
                              void* d_out, int out_size, void* d_ws, size_t ws_size,
                              hipStream_t stream) {
  const float* x      = (const float*)d_in[0];
  const float* mask   = (const float*)d_in[1];
  const float* rpb    = (const float*)d_in[2];
  const float* qkv_w  = (const float*)d_in[3];
  const float* qkv_b  = (const float*)d_in[4];
  const float* proj_w = (const float*)d_in[5];
  const float* proj_b = (const float*)d_in[6];
  const int*   rel    = (const int*)d_in[7];
  float* out = (float*)d_out;
  char* ws = (char*)d_ws;
  int B_ = in_sizes[0] / 16384;   // windows*batch
  int nW = in_sizes[1] / 4096;    // mask windows
  hipLaunchKernelGGL(prep_kernel, dim3(768), dim3(256), 0, stream,
                     qkv_w, proj_w, rpb, rel, ws);
  hipLaunchKernelGGL(fused_kernel, dim3(B_), dim3(512), 0, stream,
                     x, mask, qkv_b, proj_b, (const char*)ws, out, nW);
}